// Round 8
// baseline (245.739 us; speedup 1.0000x reference)
//
#include <hip/hip_runtime.h>

typedef unsigned short u16;
typedef __bf16 bf16x8 __attribute__((ext_vector_type(8)));
typedef float f32x4 __attribute__((ext_vector_type(4)));
typedef u16 u16x4 __attribute__((ext_vector_type(4)));

#define DEVI static __device__ __forceinline__

DEVI u16 f2bf(float f){
  unsigned u = __float_as_uint(f);
  u += 0x7FFFu + ((u >> 16) & 1u);
  return (u16)(u >> 16);
}

DEVI f32x4 mfma16(bf16x8 a, bf16x8 b, f32x4 c){
  return __builtin_amdgcn_mfma_f32_16x16x32_bf16(a, b, c, 0, 0, 0);
}

DEVI void gld16(u16* lds, const u16* g){
  __builtin_amdgcn_global_load_lds(
      (const __attribute__((address_space(1))) void*)g,
      (__attribute__((address_space(3))) void*)lds, 16, 0, 0);
}

// ---------------- fp32 -> bf16 convert ----------------
__global__ void cvt_bf16(const float* __restrict__ s, u16* __restrict__ d, int n4){
  int i = blockIdx.x * blockDim.x + threadIdx.x;
  int stride = gridDim.x * blockDim.x;
  for (; i < n4; i += stride){
    float4 v = *(const float4*)(s + (size_t)i * 4);
    u16x4 o = { f2bf(v.x), f2bf(v.y), f2bf(v.z), f2bf(v.w) };
    *(u16x4*)(d + (size_t)i * 4) = o;
  }
}

// ---------------- GEMM: C = A * Bm^T + bias ----------------
// 128x128 tile, BK=32, 256 threads (4 waves 2Mx2N, each 64x64 out).
// THREE 16KB LDS buffers (48 KB total -> 3 blocks/CU with launch_bounds
// (256,3): TLP covers barrier/drain dead time across independent blocks).
// Lead-2 staging (race-free), ONE barrier per tile, counted vmcnt(4).
// Fat-row swizzle (128B rows, 16B chunk ^= fatrow&7): linear gld_lds dest +
// inverse-swizzled global source + swizzled ds_read (conflict-free).
// MODE 0: QKV epilogue (Q,K row-major bf16; V transposed per-window).
// MODE 1: fp32 store + bias.
template<int MODE>
__global__ __launch_bounds__(256, 3)
void gemm_bt(const u16* __restrict__ A, const u16* __restrict__ Bm,
             const float* __restrict__ bias,
             u16* __restrict__ Qws, u16* __restrict__ Kws, u16* __restrict__ Vtws,
             float* __restrict__ Cf)
{
  constexpr int K = 1024;
  constexpr int NT = K / 32;                       // 32 K-tiles
  __shared__ __align__(16) u16 lds[3 * 8192];      // 48 KiB (A 8KB + B 8KB per buf)
  const int t = threadIdx.x;
  const int w = t >> 6, l = t & 63, g = l >> 4, r16 = l & 15;
  const int wm = w >> 1, wn = w & 1;

  // XCD-bijective block swizzle (nwg % 8 == 0 in both modes)
  constexpr int NBX = (MODE == 0) ? 24 : 8;
  constexpr int NWG = NBX * 128;
  const int orig = blockIdx.y * NBX + blockIdx.x;
  const int swzb = (orig & 7) * (NWG >> 3) + (orig >> 3);
  const int row0 = (swzb / NBX) * 128, col0 = (swzb % NBX) * 128;

  const f32x4 zero = {0.f, 0.f, 0.f, 0.f};
  f32x4 acc[4][4];
#pragma unroll
  for (int m = 0; m < 4; ++m)
#pragma unroll
    for (int n = 0; n < 4; ++n) acc[m][n] = zero;

  // ---- staging map: thread t -> linear 16B chunk t within a 4KB half-load.
  // fat row F = t>>3 (32 per half-load), slot s = t&7; global logical chunk
  // c = s ^ (F&7); c -> (row parity c>>2, k-chunk c&3)  [rule 21: inverse
  // swizzle on the SOURCE, linear LDS dest].
  const int F = t >> 3;
  const int cc = (t & 7) ^ (F & 7);
  const int strow = 2 * F + (cc >> 2);
  const int stk = (cc & 3) * 8;
  const u16* pA = A + (size_t)(row0 + strow) * K + stk;
  const u16* pB = Bm + (size_t)(col0 + strow) * K + stk;

  auto STAGE = [&](int buf, int kt){
    u16* dst = lds + buf * 8192 + (w << 9);        // wave-uniform base
    gld16(dst,        pA + kt);                    // A rows   0..63
    gld16(dst + 2048, pA + (size_t)64 * K + kt);   // A rows  64..127
    gld16(dst + 4096, pB + kt);                    // B rows   0..63
    gld16(dst + 6144, pB + (size_t)64 * K + kt);   // B rows  64..127
  };

  // ---- read map (swizzled): fat row R = tilerow>>1, chunk
  // c1 = ((row&1)*4 + g) ^ (R&7); u16 offset = R*64 + c1*8.
  const int c1 = (((r16 & 1) << 2) | g) ^ ((r16 >> 1) & 7);
  const int aoff = (wm * 32 + (r16 >> 1)) * 64 + c1 * 8;
  const int boff = 4096 + (wn * 32 + (r16 >> 1)) * 64 + c1 * 8;

  auto TILECOMP = [&](int buf){
    const u16* base = lds + buf * 8192;
    bf16x8 af[4], bfr[4];
#pragma unroll
    for (int m = 0; m < 4; ++m) af[m] = *(const bf16x8*)(base + aoff + m * 512);
#pragma unroll
    for (int n = 0; n < 4; ++n) bfr[n] = *(const bf16x8*)(base + boff + n * 512);
    __builtin_amdgcn_s_setprio(1);
#pragma unroll
    for (int m = 0; m < 4; ++m)
#pragma unroll
      for (int n = 0; n < 4; ++n)
        acc[m][n] = mfma16(af[m], bfr[n], acc[m][n]);
    __builtin_amdgcn_s_setprio(0);
  };

  // ---- prologue: stage tiles 0 (buf0) and 1 (buf1)
  STAGE(0, 0);
  STAGE(1, 32);
  asm volatile("s_waitcnt vmcnt(4)" ::: "memory");   // tile 0 landed
  __builtin_amdgcn_s_barrier();
  asm volatile("" ::: "memory");

  int cb = 0, sb = 2;
  for (int tt = 0; tt < NT - 2; ++tt){
    STAGE(sb, (tt + 2) * 32);
    TILECOMP(cb);
    asm volatile("s_waitcnt vmcnt(4)" ::: "memory"); // tile tt+1 landed
    __builtin_amdgcn_s_barrier();
    asm volatile("" ::: "memory");
    cb = (cb == 2) ? 0 : cb + 1;
    sb = (sb == 2) ? 0 : sb + 1;
  }
  TILECOMP(cb);                                      // tile NT-2
  cb = (cb == 2) ? 0 : cb + 1;
  asm volatile("s_waitcnt vmcnt(0)" ::: "memory");   // tile NT-1 landed
  __builtin_amdgcn_s_barrier();
  asm volatile("" ::: "memory");
  TILECOMP(cb);                                      // tile NT-1

  // ---- epilogue ----
  float bv[4];
#pragma unroll
  for (int nb = 0; nb < 4; ++nb) bv[nb] = bias[col0 + wn * 64 + nb * 16 + r16];

  if (MODE == 1){
#pragma unroll
    for (int m = 0; m < 4; ++m){
      int row = row0 + wm * 64 + m * 16 + g * 4;
#pragma unroll
      for (int nb = 0; nb < 4; ++nb){
        int n = col0 + wn * 64 + nb * 16 + r16;
#pragma unroll
        for (int j = 0; j < 4; ++j)
          Cf[(size_t)(row + j) * 1024 + n] = acc[m][nb][j] + bv[nb];
      }
    }
  } else {
    const int regn = col0 >> 10;   // uniform per block: 0=Q 1=K 2=V
    if (regn == 0){
#pragma unroll
      for (int m = 0; m < 4; ++m){
        int row = row0 + wm * 64 + m * 16 + g * 4;
#pragma unroll
        for (int nb = 0; nb < 4; ++nb){
          int n = col0 + wn * 64 + nb * 16 + r16;
#pragma unroll
          for (int j = 0; j < 4; ++j)
            Qws[(size_t)(row + j) * 1024 + n] = f2bf(acc[m][nb][j] + bv[nb]);
        }
      }
    } else if (regn == 1){
#pragma unroll
      for (int m = 0; m < 4; ++m){
        int row = row0 + wm * 64 + m * 16 + g * 4;
#pragma unroll
        for (int nb = 0; nb < 4; ++nb){
          int n = col0 + wn * 64 + nb * 16 + r16 - 1024;
#pragma unroll
          for (int j = 0; j < 4; ++j)
            Kws[(size_t)(row + j) * 1024 + n] = f2bf(acc[m][nb][j] + bv[nb]);
        }
      }
    } else {
      // V: store transposed per window: Vt[win][d][rr], win=((b*16+h)*16+wd)
#pragma unroll
      for (int m = 0; m < 4; ++m){
        int row = row0 + wm * 64 + m * 16 + g * 4;
        int bb = row >> 12, s = row & 4095;
        int wdw = s >> 8, rr = s & 255;      // rr multiple of 4
#pragma unroll
        for (int nb = 0; nb < 4; ++nb){
          int n2 = col0 + wn * 64 + nb * 16 + r16 - 2048;
          int hh = n2 >> 6, d = n2 & 63;
          int winw = (bb * 16 + hh) * 16 + wdw;
          u16x4 pk;
#pragma unroll
          for (int j = 0; j < 4; ++j) pk[j] = f2bf(acc[m][nb][j] + bv[nb]);
          *(u16x4*)(Vtws + (size_t)winw * 16384 + d * 256 + rr) = pk;
        }
      }
    }
  }
}

// ---------------- windowed attention (resident K/V, barrier-free loop) ----
// (unchanged — 1 block/window, all K/V in LDS, one barrier, no
// max-subtraction, MFMA row-sums.)
__global__ __launch_bounds__(256, 1)
void attn_win(const u16* __restrict__ Q, const u16* __restrict__ Kws,
              const u16* __restrict__ Vt, u16* __restrict__ Oo)
{
  __shared__ __align__(16) u16 Kl[16384];   // 32 KB: 4 x [64 r x 64 d]
  __shared__ __align__(16) u16 Vl[16384];   // 32 KB: [64 d][256 k]
  __shared__ __align__(16) u16 Pl[16384];   // 32 KB: 4 waves x [64 q x 64 k]
  const int t = threadIdx.x;
  const int wv = t >> 6, l = t & 63, g = l >> 4, r16 = l & 15;
  const int win = blockIdx.x;
  const int b = win >> 8, h = (win >> 4) & 15, wd = win & 15;
  const int s0 = b * 4096 + wd * 256;
  const size_t vwin = (size_t)win * 16384;

  {
    const int rloc = l >> 3, sl = l & 7;
    const u16* ksrc = Kws + (size_t)(s0 + wv * 64 + rloc) * 1024 + h * 64
                      + ((sl ^ rloc) << 3);
#pragma unroll
    for (int j = 0; j < 8; ++j)
      gld16(Kl + wv * 4096 + j * 512, ksrc + (size_t)j * 8 * 1024);
    const int dloc = l >> 5, kcv = (l >> 3) & 3, slv = l & 7;
#pragma unroll
    for (int j = 0; j < 8; ++j){
      int d = wv * 16 + j * 2 + dloc;
      gld16(Vl + (wv * 8 + j) * 512,
            Vt + vwin + (size_t)d * 256 + kcv * 64 + ((slv ^ (d & 7)) << 3));
    }
  }

  bf16x8 aq[4][2];
#pragma unroll
  for (int qm = 0; qm < 4; ++qm)
#pragma unroll
    for (int kk = 0; kk < 2; ++kk)
      aq[qm][kk] = *(const bf16x8*)(Q + (size_t)(s0 + wv * 64 + qm * 16 + r16) * 1024
                                      + h * 64 + kk * 32 + g * 8);

  const f32x4 zero = {0.f, 0.f, 0.f, 0.f};
  f32x4 o[4][4];
  f32x4 lsum[4];
#pragma unroll
  for (int qm = 0; qm < 4; ++qm){
    lsum[qm] = zero;
#pragma unroll
    for (int nd = 0; nd < 4; ++nd) o[qm][nd] = zero;
  }
  bf16x8 onesb;
#pragma unroll
  for (int e = 0; e < 8; ++e) onesb[e] = (__bf16)1.0f;

  const float cl2 = 0.125f * 1.44269504f;

  __syncthreads();

  for (int kc = 0; kc < 4; ++kc){
    f32x4 sc[4][4];
#pragma unroll
    for (int qm = 0; qm < 4; ++qm)
#pragma unroll
      for (int nb = 0; nb < 4; ++nb) sc[qm][nb] = zero;
#pragma unroll
    for (int kk = 0; kk < 2; ++kk){
      bf16x8 kb[4];
#pragma unroll
      for (int nb = 0; nb < 4; ++nb)
        kb[nb] = *(const bf16x8*)(Kl + kc * 4096 + (nb * 16 + r16) * 64
                                  + ((((kk << 2) | g) ^ (r16 & 7)) << 3));
#pragma unroll
      for (int qm = 0; qm < 4; ++qm)
#pragma unroll
        for (int nb = 0; nb < 4; ++nb)
          sc[qm][nb] = mfma16(aq[qm][kk], kb[nb], sc[qm][nb]);
    }

#pragma unroll
    for (int qm = 0; qm < 4; ++qm){
#pragma unroll
      for (int j = 0; j < 4; ++j){
        int q = qm * 16 + g * 4 + j;
        u16* pbase = Pl + wv * 4096 + q * 64;
#pragma unroll
        for (int nb = 0; nb < 4; ++nb){
          float p = __builtin_amdgcn_exp2f(sc[qm][nb][j] * cl2);
          int k = nb * 16 + r16;
          pbase[(k & 7) + (((k >> 3) ^ (q & 7)) << 3)] = f2bf(p);
        }
      }
    }

#pragma unroll
    for (int kc32 = 0; kc32 < 2; ++kc32){
      bf16x8 pa[4], vb[4];
#pragma unroll
      for (int qm = 0; qm < 4; ++qm)
        pa[qm] = *(const bf16x8*)(Pl + wv * 4096 + (qm * 16 + r16) * 64
                                  + ((((kc32 << 2) | g) ^ (r16 & 7)) << 3));
#pragma unroll
      for (int nd = 0; nd < 4; ++nd){
        int d = nd * 16 + r16;
        vb[nd] = *(const bf16x8*)(Vl + d * 256 + kc * 64
                                  + ((((kc32 << 2) | g) ^ (r16 & 7)) << 3));
      }
#pragma unroll
      for (int qm = 0; qm < 4; ++qm){
        lsum[qm] = mfma16(pa[qm], onesb, lsum[qm]);
#pragma unroll
        for (int nd = 0; nd < 4; ++nd)
          o[qm][nd] = mfma16(pa[qm], vb[nd], o[qm][nd]);
      }
    }
  }

#pragma unroll
  for (int qm = 0; qm < 4; ++qm){
#pragma unroll
    for (int j = 0; j < 4; ++j){
      float inv = 1.f / lsum[qm][j];
      int row = s0 + wv * 64 + qm * 16 + g * 4 + j;
#pragma unroll
      for (int nd = 0; nd < 4; ++nd)
        Oo[(size_t)row * 1024 + h * 64 + nd * 16 + r16] = f2bf(o[qm][nd][j] * inv);
    }
  }
}

// ---------------- launch ----------------
extern "C" void kernel_launch(void* const* d_in, const int* in_sizes, int n_in,
                              void* d_out, int out_size, void* d_ws, size_t ws_size,
                              hipStream_t stream)
{
  (void)in_sizes; (void)n_in; (void)out_size; (void)ws_size;
  const float* x  = (const float*)d_in[0];
  const float* Wq = (const float*)d_in[1];
  const float* bq = (const float*)d_in[2];
  const float* Wo = (const float*)d_in[3];
  const float* bo = (const float*)d_in[4];

  char* ws = (char*)d_ws;
  const size_t SZ = (size_t)16384 * 1024 * 2;          // 33.5 MB
  u16* xb  = (u16*)(ws);                               // x bf16, later reused for attn out
  u16* Vt  = (u16*)(ws + SZ);                          // V transposed per window
  u16* wqb = (u16*)(ws + 2 * SZ);                      // W_qkv bf16 (6.29 MB)
  u16* wob = (u16*)(ws + 2 * SZ + 6291456);            // W_out bf16 (2.1 MB)
  u16* Qws = (u16*)d_out;
  u16* Kws = (u16*)d_out + (size_t)16384 * 1024;

  cvt_bf16<<<2048, 256, 0, stream>>>(x,  xb,  16777216 / 4);
  cvt_bf16<<<768,  256, 0, stream>>>(Wq, wqb, 3145728 / 4);
  cvt_bf16<<<256,  256, 0, stream>>>(Wo, wob, 1048576 / 4);

  gemm_bt<0><<<dim3(24, 128), 256, 0, stream>>>(xb, wqb, bq, Qws, Kws, Vt, nullptr);

  attn_win<<<1024, 256, 0, stream>>>(Qws, Kws, Vt, xb);

  gemm_bt<1><<<dim3(8, 128), 256, 0, stream>>>(xb, wob, bo,
                                               nullptr, nullptr, nullptr,
                                               (float*)d_out);
}

// Round 9
// 214.792 us; speedup vs baseline: 1.1441x; 1.1441x over previous
//
#include <hip/hip_runtime.h>

typedef unsigned short u16;
typedef __bf16 bf16x8 __attribute__((ext_vector_type(8)));
typedef float f32x4 __attribute__((ext_vector_type(4)));
typedef u16 u16x4 __attribute__((ext_vector_type(4)));

#define DEVI static __device__ __forceinline__

DEVI u16 f2bf(float f){
  unsigned u = __float_as_uint(f);
  u += 0x7FFFu + ((u >> 16) & 1u);
  return (u16)(u >> 16);
}

DEVI f32x4 mfma16(bf16x8 a, bf16x8 b, f32x4 c){
  return __builtin_amdgcn_mfma_f32_16x16x32_bf16(a, b, c, 0, 0, 0);
}

DEVI void gld16(u16* lds, const u16* g){
  __builtin_amdgcn_global_load_lds(
      (const __attribute__((address_space(1))) void*)g,
      (__attribute__((address_space(3))) void*)lds, 16, 0, 0);
}

// ---------------- fp32 -> bf16 convert ----------------
__global__ void cvt_bf16(const float* __restrict__ s, u16* __restrict__ d, int n4){
  int i = blockIdx.x * blockDim.x + threadIdx.x;
  int stride = gridDim.x * blockDim.x;
  for (; i < n4; i += stride){
    float4 v = *(const float4*)(s + (size_t)i * 4);
    u16x4 o = { f2bf(v.x), f2bf(v.y), f2bf(v.z), f2bf(v.w) };
    *(u16x4*)(d + (size_t)i * 4) = o;
  }
}

// ---------------- GEMM: C = A * Bm^T + bias ----------------
// 256x256 tile, BK=32, 1024 threads (16 waves 4Mx4N, each 64x64 out).
// Per-wave acc = 64 regs (vs 128 at 8-wave 256^2) -> with
// __launch_bounds__(1024,4) total regs <=128 => 4 waves/SIMD (50% occ),
// DOUBLE the 8-wave config, while keeping full 256-dim A/B reuse
// (R8 showed 128^2 tiles triple FETCH_SIZE -> regression).
// THREE 32KB LDS buffers (96 KiB), lead-2 staging (race-free), ONE
// barrier per tile, counted vmcnt(2) (2 loads/tile; never 0 mid-loop).
// Fat-row swizzle (128B rows, 16B chunk ^= fatrow&7): linear gld_lds dest
// + inverse-swizzled global source + swizzled ds_read (conflicts = 0).
// MODE 0: QKV epilogue (Q,K row-major bf16; V transposed per-window).
// MODE 1: fp32 store + bias.
template<int MODE>
__global__ __launch_bounds__(1024, 4)
void gemm_bt(const u16* __restrict__ A, const u16* __restrict__ Bm,
             const float* __restrict__ bias,
             u16* __restrict__ Qws, u16* __restrict__ Kws, u16* __restrict__ Vtws,
             float* __restrict__ Cf)
{
  constexpr int K = 1024;
  constexpr int NT = K / 32;                       // 32 K-tiles
  __shared__ __align__(16) u16 lds[3 * 16384];     // 96 KiB (A 16KB + B 16KB per buf)
  const int t = threadIdx.x;
  const int w = t >> 6, l = t & 63, g = l >> 4, r16 = l & 15;
  const int wm = w >> 2, wn = w & 3;               // 4Mx4N wave grid

  // XCD-bijective block swizzle (nwg % 8 == 0 in both modes)
  constexpr int NBX = (MODE == 0) ? 12 : 4;
  constexpr int NWG = NBX * 64;
  const int orig = blockIdx.y * NBX + blockIdx.x;
  const int swzb = (orig & 7) * (NWG >> 3) + (orig >> 3);
  const int row0 = (swzb / NBX) * 256, col0 = (swzb % NBX) * 256;

  const f32x4 zero = {0.f, 0.f, 0.f, 0.f};
  f32x4 acc[4][4];
#pragma unroll
  for (int m = 0; m < 4; ++m)
#pragma unroll
    for (int n = 0; n < 4; ++n) acc[m][n] = zero;

  // ---- staging map: 1024 threads cover the 16KB A region (1024 x 16B
  // chunks) in ONE gld16, ditto B. fat row F = t>>3 (128 per region, 2 tile
  // rows each), slot s = t&7; global logical chunk c = s ^ (F&7);
  // c -> (row parity c>>2, k-chunk c&3)   [rule 21: inverse swizzle on the
  // SOURCE, linear LDS dest].
  const int F = t >> 3;
  const int cc = (t & 7) ^ (F & 7);
  const int strow = 2 * F + (cc >> 2);
  const int stk = (cc & 3) * 8;
  const u16* pA = A + (size_t)(row0 + strow) * K + stk;
  const u16* pB = Bm + (size_t)(col0 + strow) * K + stk;

  auto STAGE = [&](int buf, int kt){
    u16* dst = lds + buf * 16384 + (w << 9);       // wave-uniform base (1KB/wave)
    gld16(dst,        pA + kt);                    // A rows 0..255
    gld16(dst + 8192, pB + kt);                    // B rows 0..255
  };

  // ---- read map (swizzled): fat row R = tilerow>>1, chunk
  // c1 = ((row&1)*4 + g) ^ (R&7); u16 offset = R*64 + c1*8.
  const int c1 = (((r16 & 1) << 2) | g) ^ ((r16 >> 1) & 7);
  const int aoff = (wm * 32 + (r16 >> 1)) * 64 + c1 * 8;
  const int boff = 8192 + (wn * 32 + (r16 >> 1)) * 64 + c1 * 8;

  auto TILECOMP = [&](int buf){
    const u16* base = lds + buf * 16384;
    bf16x8 af[4], bfr[4];
#pragma unroll
    for (int m = 0; m < 4; ++m) af[m] = *(const bf16x8*)(base + aoff + m * 512);
#pragma unroll
    for (int n = 0; n < 4; ++n) bfr[n] = *(const bf16x8*)(base + boff + n * 512);
    __builtin_amdgcn_s_setprio(1);
#pragma unroll
    for (int m = 0; m < 4; ++m)
#pragma unroll
      for (int n = 0; n < 4; ++n)
        acc[m][n] = mfma16(af[m], bfr[n], acc[m][n]);
    __builtin_amdgcn_s_setprio(0);
  };

  // ---- prologue: stage tiles 0 (buf0) and 1 (buf1)
  STAGE(0, 0);
  STAGE(1, 32);
  asm volatile("s_waitcnt vmcnt(2)" ::: "memory");   // tile 0 landed
  __builtin_amdgcn_s_barrier();
  asm volatile("" ::: "memory");

  int cb = 0, sb = 2;
  for (int tt = 0; tt < NT - 2; ++tt){
    STAGE(sb, (tt + 2) * 32);
    TILECOMP(cb);
    asm volatile("s_waitcnt vmcnt(2)" ::: "memory"); // tile tt+1 landed
    __builtin_amdgcn_s_barrier();
    asm volatile("" ::: "memory");
    cb = (cb == 2) ? 0 : cb + 1;
    sb = (sb == 2) ? 0 : sb + 1;
  }
  TILECOMP(cb);                                      // tile NT-2
  cb = (cb == 2) ? 0 : cb + 1;
  asm volatile("s_waitcnt vmcnt(0)" ::: "memory");   // tile NT-1 landed
  __builtin_amdgcn_s_barrier();
  asm volatile("" ::: "memory");
  TILECOMP(cb);                                      // tile NT-1

  // ---- epilogue ----
  float bv[4];
#pragma unroll
  for (int nb = 0; nb < 4; ++nb) bv[nb] = bias[col0 + wn * 64 + nb * 16 + r16];

  if (MODE == 1){
#pragma unroll
    for (int m = 0; m < 4; ++m){
      int row = row0 + wm * 64 + m * 16 + g * 4;
#pragma unroll
      for (int nb = 0; nb < 4; ++nb){
        int n = col0 + wn * 64 + nb * 16 + r16;
#pragma unroll
        for (int j = 0; j < 4; ++j)
          Cf[(size_t)(row + j) * 1024 + n] = acc[m][nb][j] + bv[nb];
      }
    }
  } else {
    const int regn = col0 >> 10;   // uniform per block: 0=Q 1=K 2=V
    if (regn == 0){
#pragma unroll
      for (int m = 0; m < 4; ++m){
        int row = row0 + wm * 64 + m * 16 + g * 4;
#pragma unroll
        for (int nb = 0; nb < 4; ++nb){
          int n = col0 + wn * 64 + nb * 16 + r16;
#pragma unroll
          for (int j = 0; j < 4; ++j)
            Qws[(size_t)(row + j) * 1024 + n] = f2bf(acc[m][nb][j] + bv[nb]);
        }
      }
    } else if (regn == 1){
#pragma unroll
      for (int m = 0; m < 4; ++m){
        int row = row0 + wm * 64 + m * 16 + g * 4;
#pragma unroll
        for (int nb = 0; nb < 4; ++nb){
          int n = col0 + wn * 64 + nb * 16 + r16 - 1024;
#pragma unroll
          for (int j = 0; j < 4; ++j)
            Kws[(size_t)(row + j) * 1024 + n] = f2bf(acc[m][nb][j] + bv[nb]);
        }
      }
    } else {
      // V: store transposed per window: Vt[win][d][rr], win=((b*16+h)*16+wd)
#pragma unroll
      for (int m = 0; m < 4; ++m){
        int row = row0 + wm * 64 + m * 16 + g * 4;
        int bb = row >> 12, s = row & 4095;
        int wdw = s >> 8, rr = s & 255;      // rr multiple of 4
#pragma unroll
        for (int nb = 0; nb < 4; ++nb){
          int n2 = col0 + wn * 64 + nb * 16 + r16 - 2048;
          int hh = n2 >> 6, d = n2 & 63;
          int winw = (bb * 16 + hh) * 16 + wdw;
          u16x4 pk;
#pragma unroll
          for (int j = 0; j < 4; ++j) pk[j] = f2bf(acc[m][nb][j] + bv[nb]);
          *(u16x4*)(Vtws + (size_t)winw * 16384 + d * 256 + rr) = pk;
        }
      }
    }
  }
}

// ---------------- windowed attention (resident K/V, barrier-free loop) ----
// (unchanged — 1 block/window, all K/V in LDS, one barrier, no
// max-subtraction, MFMA row-sums.)
__global__ __launch_bounds__(256, 1)
void attn_win(const u16* __restrict__ Q, const u16* __restrict__ Kws,
              const u16* __restrict__ Vt, u16* __restrict__ Oo)
{
  __shared__ __align__(16) u16 Kl[16384];   // 32 KB: 4 x [64 r x 64 d]
  __shared__ __align__(16) u16 Vl[16384];   // 32 KB: [64 d][256 k]
  __shared__ __align__(16) u16 Pl[16384];   // 32 KB: 4 waves x [64 q x 64 k]
  const int t = threadIdx.x;
  const int wv = t >> 6, l = t & 63, g = l >> 4, r16 = l & 15;
  const int win = blockIdx.x;
  const int b = win >> 8, h = (win >> 4) & 15, wd = win & 15;
  const int s0 = b * 4096 + wd * 256;
  const size_t vwin = (size_t)win * 16384;

  {
    const int rloc = l >> 3, sl = l & 7;
    const u16* ksrc = Kws + (size_t)(s0 + wv * 64 + rloc) * 1024 + h * 64
                      + ((sl ^ rloc) << 3);
#pragma unroll
    for (int j = 0; j < 8; ++j)
      gld16(Kl + wv * 4096 + j * 512, ksrc + (size_t)j * 8 * 1024);
    const int dloc = l >> 5, kcv = (l >> 3) & 3, slv = l & 7;
#pragma unroll
    for (int j = 0; j < 8; ++j){
      int d = wv * 16 + j * 2 + dloc;
      gld16(Vl + (wv * 8 + j) * 512,
            Vt + vwin + (size_t)d * 256 + kcv * 64 + ((slv ^ (d & 7)) << 3));
    }
  }

  bf16x8 aq[4][2];
#pragma unroll
  for (int qm = 0; qm < 4; ++qm)
#pragma unroll
    for (int kk = 0; kk < 2; ++kk)
      aq[qm][kk] = *(const bf16x8*)(Q + (size_t)(s0 + wv * 64 + qm * 16 + r16) * 1024
                                      + h * 64 + kk * 32 + g * 8);

  const f32x4 zero = {0.f, 0.f, 0.f, 0.f};
  f32x4 o[4][4];
  f32x4 lsum[4];
#pragma unroll
  for (int qm = 0; qm < 4; ++qm){
    lsum[qm] = zero;
#pragma unroll
    for (int nd = 0; nd < 4; ++nd) o[qm][nd] = zero;
  }
  bf16x8 onesb;
#pragma unroll
  for (int e = 0; e < 8; ++e) onesb[e] = (__bf16)1.0f;

  const float cl2 = 0.125f * 1.44269504f;

  __syncthreads();

  for (int kc = 0; kc < 4; ++kc){
    f32x4 sc[4][4];
#pragma unroll
    for (int qm = 0; qm < 4; ++qm)
#pragma unroll
      for (int nb = 0; nb < 4; ++nb) sc[qm][nb] = zero;
#pragma unroll
    for (int kk = 0; kk < 2; ++kk){
      bf16x8 kb[4];
#pragma unroll
      for (int nb = 0; nb < 4; ++nb)
        kb[nb] = *(const bf16x8*)(Kl + kc * 4096 + (nb * 16 + r16) * 64
                                  + ((((kk << 2) | g) ^ (r16 & 7)) << 3));
#pragma unroll
      for (int qm = 0; qm < 4; ++qm)
#pragma unroll
        for (int nb = 0; nb < 4; ++nb)
          sc[qm][nb] = mfma16(aq[qm][kk], kb[nb], sc[qm][nb]);
    }

#pragma unroll
    for (int qm = 0; qm < 4; ++qm){
#pragma unroll
      for (int j = 0; j < 4; ++j){
        int q = qm * 16 + g * 4 + j;
        u16* pbase = Pl + wv * 4096 + q * 64;
#pragma unroll
        for (int nb = 0; nb < 4; ++nb){
          float p = __builtin_amdgcn_exp2f(sc[qm][nb][j] * cl2);
          int k = nb * 16 + r16;
          pbase[(k & 7) + (((k >> 3) ^ (q & 7)) << 3)] = f2bf(p);
        }
      }
    }

#pragma unroll
    for (int kc32 = 0; kc32 < 2; ++kc32){
      bf16x8 pa[4], vb[4];
#pragma unroll
      for (int qm = 0; qm < 4; ++qm)
        pa[qm] = *(const bf16x8*)(Pl + wv * 4096 + (qm * 16 + r16) * 64
                                  + ((((kc32 << 2) | g) ^ (r16 & 7)) << 3));
#pragma unroll
      for (int nd = 0; nd < 4; ++nd){
        int d = nd * 16 + r16;
        vb[nd] = *(const bf16x8*)(Vl + d * 256 + kc * 64
                                  + ((((kc32 << 2) | g) ^ (r16 & 7)) << 3));
      }
#pragma unroll
      for (int qm = 0; qm < 4; ++qm){
        lsum[qm] = mfma16(pa[qm], onesb, lsum[qm]);
#pragma unroll
        for (int nd = 0; nd < 4; ++nd)
          o[qm][nd] = mfma16(pa[qm], vb[nd], o[qm][nd]);
      }
    }
  }

#pragma unroll
  for (int qm = 0; qm < 4; ++qm){
#pragma unroll
    for (int j = 0; j < 4; ++j){
      float inv = 1.f / lsum[qm][j];
      int row = s0 + wv * 64 + qm * 16 + g * 4 + j;
#pragma unroll
      for (int nd = 0; nd < 4; ++nd)
        Oo[(size_t)row * 1024 + h * 64 + nd * 16 + r16] = f2bf(o[qm][nd][j] * inv);
    }
  }
}

// ---------------- launch ----------------
extern "C" void kernel_launch(void* const* d_in, const int* in_sizes, int n_in,
                              void* d_out, int out_size, void* d_ws, size_t ws_size,
                              hipStream_t stream)
{
  (void)in_sizes; (void)n_in; (void)out_size; (void)ws_size;
  const float* x  = (const float*)d_in[0];
  const float* Wq = (const float*)d_in[1];
  const float* bq = (const float*)d_in[2];
  const float* Wo = (const float*)d_in[3];
  const float* bo = (const float*)d_in[4];

  char* ws = (char*)d_ws;
  const size_t SZ = (size_t)16384 * 1024 * 2;          // 33.5 MB
  u16* xb  = (u16*)(ws);                               // x bf16, later reused for attn out
  u16* Vt  = (u16*)(ws + SZ);                          // V transposed per window
  u16* wqb = (u16*)(ws + 2 * SZ);                      // W_qkv bf16 (6.29 MB)
  u16* wob = (u16*)(ws + 2 * SZ + 6291456);            // W_out bf16 (2.1 MB)
  u16* Qws = (u16*)d_out;
  u16* Kws = (u16*)d_out + (size_t)16384 * 1024;

  cvt_bf16<<<2048, 256, 0, stream>>>(x,  xb,  16777216 / 4);
  cvt_bf16<<<768,  256, 0, stream>>>(Wq, wqb, 3145728 / 4);
  cvt_bf16<<<256,  256, 0, stream>>>(Wo, wob, 1048576 / 4);

  gemm_bt<0><<<dim3(12, 64), 1024, 0, stream>>>(xb, wqb, bq, Qws, Kws, Vt, nullptr);

  attn_win<<<1024, 256, 0, stream>>>(Qws, Kws, Vt, xb);

  gemm_bt<1><<<dim3(4, 64), 1024, 0, stream>>>(xb, wob, bo,
                                               nullptr, nullptr, nullptr,
                                               (float*)d_out);
}